// Round 3
// baseline (307.230 us; speedup 1.0000x reference)
//
#include <hip/hip_runtime.h>
#include <stdint.h>

#define B_   32
#define CIN  64
#define COUT 64
#define H_   128
#define W_   128
#define WP   130
#define HW_  (H_ * W_)

typedef __bf16 bf16x8 __attribute__((ext_vector_type(8)));
typedef float  f32x4  __attribute__((ext_vector_type(4)));

__device__ inline unsigned int f2bf(float f) {
  union { float f; unsigned u; } uf; uf.f = f;
  unsigned u = uf.u;
  unsigned r = 0x7FFFu + ((u >> 16) & 1u);
  return (u + r) >> 16;
}

// pack two floats -> one dword of 2x bf16 (v_cvt_pk_bf16_f32)
__device__ inline unsigned int pk2(float a, float b) {
  unsigned short x = __builtin_bit_cast(unsigned short, (__bf16)a);
  unsigned short y = __builtin_bit_cast(unsigned short, (__bf16)b);
  return (unsigned int)x | ((unsigned int)y << 16);
}

// Wb[b][p][cout][cin] = bf16(W0 + cov[b]*W1), p = kh*3+kw
__global__ __launch_bounds__(256) void prep_w(const float* __restrict__ W0,
                                              const float* __restrict__ W1,
                                              const float* __restrict__ cov,
                                              unsigned short* __restrict__ Wb) {
  int g  = blockIdx.x * 256 + threadIdx.x;   // [0, 32*9*64*64)
  int ci = g & 63;
  int co = (g >> 6) & 63;
  int v  = g >> 12;                          // b*9 + p
  int b  = v / 9;
  int p  = v - b * 9;
  int widx = (co * CIN + ci) * 9 + p;
  float val = W0[widx] + cov[b] * W1[widx];
  Wb[g] = (unsigned short)f2bf(val);
}

// Persistent strip kernel. Grid = 32 b x 16 strips (8 output rows each) = 512
// blocks x 512 threads = all resident (2 blocks/CU). LDS = ring of 4 input
// rows; each step (2 output rows): prefetch next 2 input rows to REGISTERS
// before compute (T14), compute 9 taps from ring, barrier, ds_write staged
// rows into the 2 vacated slots, store outputs, barrier. Memory flow is
// steady-state instead of burst/phase-locked.
// Row ih lives in slot (ih+1)&3 (h0 % 8 == 0). LDS row layout as before:
// [w' 0..129][ci-octet slot = (ci>>3)^(w'&7)][ci&7], bf16.
__global__ __launch_bounds__(512, 4) void conv_strip(
    const float* __restrict__ X,
    const unsigned short* __restrict__ Wb,
    float* __restrict__ out) {
  __shared__ __align__(16) unsigned short Xs[4 * WP * 64];  // 66,560 B

  int bid   = blockIdx.x;          // b*16 + strip
  int b     = bid >> 4;
  int strip = bid & 15;
  int h0    = strip * 8;
  int t  = threadIdx.x;
  int wv = t >> 6;                 // wave 0..7
  int l  = t & 63;

  // ---- initial fill: rows ih = h0-1 .. h0+2 -> slots 0..3 ----
  {
    int r    = wv >> 1;
    int half = wv & 1;
    unsigned short* dst_row = Xs + r * (WP * 64);
    // persistent halo columns w'=0 / w'=129 (never overwritten by staging)
    unsigned int* d32 = (unsigned int*)(dst_row + half * (129 * 64));
    if (l < 32) d32[l] = 0u;

    int ih = h0 - 1 + r;
    if (ih < 0) {                  // only strip 0, r=0
      int4 z = {0, 0, 0, 0};
      int4* d = (int4*)(dst_row + 64);
      #pragma unroll
      for (int kk = 0; kk < 8; kk++) d[half * 512 + kk * 64 + l] = z;
    } else {
      const float* src = X + (((size_t)b * CIN + half * 32) * H_ + ih) * W_ + (l << 1);
      int wp0 = (l << 1) + 1, wp1 = (l << 1) + 2;
      unsigned short* base0 = dst_row + wp0 * 64;
      unsigned short* base1 = dst_row + wp1 * 64;
      int s0 = wp0 & 7, s1 = wp1 & 7;
      #pragma unroll 2
      for (int g = 0; g < 32; g += 4) {
        const float* s = src + (size_t)g * HW_;
        float2 a0 = *(const float2*)(s);
        float2 a1 = *(const float2*)(s + HW_);
        float2 a2 = *(const float2*)(s + 2 * HW_);
        float2 a3 = *(const float2*)(s + 3 * HW_);
        uint2 v0, v1;
        v0.x = pk2(a0.x, a1.x); v0.y = pk2(a2.x, a3.x);
        v1.x = pk2(a0.y, a1.y); v1.y = pk2(a2.y, a3.y);
        int ci = half * 32 + g;
        int o = ci >> 3, pos = ci & 7;
        *(uint2*)(base0 + ((o ^ s0) << 3) + pos) = v0;
        *(uint2*)(base1 + ((o ^ s1) << 3) + pos) = v1;
      }
    }
  }

  // ---- role constants ----
  int cq = wv & 3;    // compute: pixel quarter | staging: ci quarter
  int a  = wv >> 2;   // compute: cout half    | staging: row select
  int lh = l & 15;
  int q  = l >> 4;
  int rbase[4], cbase[4];
  #pragma unroll
  for (int nt = 0; nt < 4; nt++) {
    int p = cq * 64 + nt * 16 + lh;
    rbase[nt] = p >> 7;
    cbase[nt] = p & 127;
  }
  const unsigned short* wbase = Wb + (size_t)b * 9 * 4096 + (size_t)(a * 32) * 64;
  const float* sbase = X + (((size_t)b * CIN + cq * 16) * H_) * W_ + (l << 1);
  int wp0 = (l << 1) + 1, wp1 = wp0 + 1;
  int sw0 = wp0 & 7, sw1 = wp1 & 7;

  __syncthreads();

  #pragma unroll 1
  for (int k = 0; k < 4; k++) {
    int h0s = h0 + 2 * k;

    // (1) issue next-step staged loads (registers), before compute
    float2 st[16];
    bool stg = (k < 3);
    int ih = h0s + 3 + a;
    if (stg && ih <= 127) {
      const float* sp = sbase + (size_t)ih * W_;
      #pragma unroll
      for (int g = 0; g < 16; g++) st[g] = *(const float2*)(sp + (size_t)g * HW_);
    } else {
      #pragma unroll
      for (int g = 0; g < 16; g++) st[g] = (float2){0.f, 0.f};
    }

    // (2) compute from ring
    f32x4 acc[2][4];
    #pragma unroll
    for (int i = 0; i < 2; i++)
      #pragma unroll
      for (int j = 0; j < 4; j++) acc[i][j] = (f32x4){0.f, 0.f, 0.f, 0.f};

    #pragma unroll 1
    for (int kh = 0; kh < 3; kh++) {
      #pragma unroll 1
      for (int kw = 0; kw < 3; kw++) {
        const unsigned short* wk = wbase + (kh * 3 + kw) * 4096;
        #pragma unroll 1
        for (int ck = 0; ck < 2; ck++) {
          bf16x8 af[2], bfr[4];
          #pragma unroll
          for (int mt = 0; mt < 2; mt++)
            af[mt] = *(const bf16x8*)(wk + (mt * 16 + lh) * 64 + ck * 32 + q * 8);
          #pragma unroll
          for (int nt = 0; nt < 4; nt++) {
            int slot = (2 * k + rbase[nt] + kh) & 3;  // ring slot of row ih
            int c = cbase[nt] + kw;
            int blk = (ck * 4 + q) ^ (c & 7);         // undo XOR swizzle
            bfr[nt] = *(const bf16x8*)(Xs + (slot * WP + c) * 64 + blk * 8);
          }
          __builtin_amdgcn_s_setprio(1);
          #pragma unroll
          for (int mt = 0; mt < 2; mt++)
            #pragma unroll
            for (int nt = 0; nt < 4; nt++)
              acc[mt][nt] = __builtin_amdgcn_mfma_f32_16x16x32_bf16(
                  af[mt], bfr[nt], acc[mt][nt], 0, 0, 0);
          __builtin_amdgcn_s_setprio(0);
        }
      }
    }

    __syncthreads();   // all waves done READING the 2 slots we overwrite

    // (3) convert + write staged rows into vacated slots
    if (stg) {
      int slot = (2 * k + a) & 3;
      unsigned short* dr = Xs + slot * (WP * 64);
      #pragma unroll
      for (int j = 0; j < 2; j++) {
        int o = cq * 2 + j;
        uint4 v0, v1;
        v0.x = pk2(st[j*8+0].x, st[j*8+1].x);
        v0.y = pk2(st[j*8+2].x, st[j*8+3].x);
        v0.z = pk2(st[j*8+4].x, st[j*8+5].x);
        v0.w = pk2(st[j*8+6].x, st[j*8+7].x);
        v1.x = pk2(st[j*8+0].y, st[j*8+1].y);
        v1.y = pk2(st[j*8+2].y, st[j*8+3].y);
        v1.z = pk2(st[j*8+4].y, st[j*8+5].y);
        v1.w = pk2(st[j*8+6].y, st[j*8+7].y);
        *(uint4*)(dr + wp0 * 64 + ((o ^ sw0) << 3)) = v0;
        *(uint4*)(dr + wp1 * 64 + ((o ^ sw1) << 3)) = v1;
      }
    }

    // (4) epilogue for this step (overlaps other waves' barrier wait)
    #pragma unroll
    for (int mt = 0; mt < 2; mt++) {
      int coutb = a * 32 + mt * 16 + q * 4;
      #pragma unroll
      for (int nt = 0; nt < 4; nt++) {
        int oh = h0s + rbase[nt];
        int ow = cbase[nt];
        #pragma unroll
        for (int r = 0; r < 4; r++) {
          int cout = coutb + r;
          out[(((size_t)b * COUT + cout) * H_ + oh) * W_ + ow] = acc[mt][nt][r];
        }
      }
    }

    if (stg) __syncthreads();   // staged rows visible before next compute
  }
}

extern "C" void kernel_launch(void* const* d_in, const int* in_sizes, int n_in,
                              void* d_out, int out_size, void* d_ws, size_t ws_size,
                              hipStream_t stream) {
  const float* x   = (const float*)d_in[0];
  const float* cov = (const float*)d_in[1];
  const float* W0  = (const float*)d_in[2];
  const float* W1  = (const float*)d_in[3];
  float* out = (float*)d_out;

  unsigned short* Wb = (unsigned short*)d_ws;   // 32*9*64*64*2 = 4,718,592 B

  prep_w    <<<dim3(4608), dim3(256), 0, stream>>>(W0, W1, cov, Wb);
  conv_strip<<<dim3(512),  dim3(512), 0, stream>>>(x, Wb, out);
}

// Round 4
// 284.685 us; speedup vs baseline: 1.0792x; 1.0792x over previous
//
#include <hip/hip_runtime.h>
#include <stdint.h>

#define B_   32
#define CIN  64
#define COUT 64
#define H_   128
#define W_   128
#define WP   130
#define HW_  (H_ * W_)
#define SLOT (WP * 64)          // shorts per LDS row slot (16,640 B)

typedef __bf16 bf16x8 __attribute__((ext_vector_type(8)));
typedef float  f32x4  __attribute__((ext_vector_type(4)));

__device__ inline unsigned int f2bf(float f) {
  union { float f; unsigned u; } uf; uf.f = f;
  unsigned u = uf.u;
  unsigned r = 0x7FFFu + ((u >> 16) & 1u);
  return (u + r) >> 16;
}

// pack two floats -> one dword of 2x bf16 (v_cvt_pk_bf16_f32)
__device__ inline unsigned int pk2(float a, float b) {
  unsigned short x = __builtin_bit_cast(unsigned short, (__bf16)a);
  unsigned short y = __builtin_bit_cast(unsigned short, (__bf16)b);
  return (unsigned int)x | ((unsigned int)y << 16);
}

// Weights pre-packed in MFMA-fragment order so the conv kernel's A-operand
// load is one fully-coalesced 1024B b128 per wave:
// Wb[b][p][ck][cq4][l][j] = bf16(W0+cov*W1) at cout=cq4*16+(l&15),
// ci=ck*32+(l>>4)*8+j, p=kh*3+kw.
__global__ __launch_bounds__(256) void prep_w(const float* __restrict__ W0,
                                              const float* __restrict__ W1,
                                              const float* __restrict__ cov,
                                              unsigned short* __restrict__ Wb) {
  int g   = blockIdx.x * 256 + threadIdx.x;  // [0, 32*9*64*64)
  int j   = g & 7;
  int l   = (g >> 3) & 63;
  int cq4 = (g >> 9) & 3;
  int ck  = (g >> 11) & 1;
  int v   = g >> 12;                         // b*9 + p
  int b   = v / 9;
  int p   = v - b * 9;
  int cout = cq4 * 16 + (l & 15);
  int ci   = ck * 32 + (l >> 4) * 8 + j;
  int widx = (cout * CIN + ci) * 9 + p;
  float val = W0[widx] + cov[b] * W1[widx];
  Wb[g] = (unsigned short)f2bf(val);
}

// Persistent strip conv: 256 blocks (1/CU) x 1024 threads (16 waves).
// Strip = 16 output rows, 8 steps of 2 rows. LDS = 6-slot input-row ring
// (99,840 B); slot(g) = g%6 for local row g = ih-(h0-1).
// Step k: [k>0: convert+ds_write rows g=2k+2,2k+3 (loaded step k-1) into
// slots freed at step k-2] -> lgkmcnt(0)+s_barrier (NO vmcnt drain: stores
// and staged loads stay in flight) -> issue loads rows g=2k+4,2k+5 ->
// compute 9 taps from slots 2k..2k+3 -> store 2 output rows.
__global__ __launch_bounds__(1024, 4) void conv_strip(
    const float* __restrict__ X,
    const unsigned short* __restrict__ Wb,
    float* __restrict__ out) {
  __shared__ __align__(16) unsigned short Xs[6 * SLOT];  // 99,840 B

  // XCD swizzle: XCD x (bid&7) owns batches 4x..4x+3 -> weight slice L2-hot
  int bid   = blockIdx.x;
  int b     = (bid & 7) * 4 + (bid >> 6);
  int strip = (bid >> 3) & 7;
  int h0    = strip * 16;

  int t  = threadIdx.x;
  int wv = t >> 6;                 // wave 0..15
  int l  = t & 63;
  int lh = l & 15;
  int q  = l >> 4;

  // staging roles: a = row (0/1), o = ci octet (0..7)
  int a = wv >> 3;
  int o = wv & 7;
  // compute roles: cq4 = cout quarter, pq = pixel quarter
  int cq4 = wv & 3;
  int pq  = wv >> 2;
  int rbase  = pq >> 1;                      // wave-uniform row within step
  int cbase0 = (pq & 1) * 64 + lh;           // + nt*16 -> pixel column

  int wp0 = 2 * l + 1, wp1 = 2 * l + 2;      // staging pixel slots
  int sw0 = (o ^ (wp0 & 7)) << 3, sw1 = (o ^ (wp1 & 7)) << 3;

  // ---- prologue: halo columns + rows g=0..3 into slots 0..3 ----
  if (wv < 6) {
    unsigned int* d32 = (unsigned int*)(Xs + wv * SLOT + (l < 32 ? 0 : 129 * 64));
    d32[l & 31] = 0u;
  }
  {
    int r  = wv >> 2;                        // 0..3
    int ih = h0 - 1 + r;
    unsigned short* dr = Xs + r * SLOT;
    #pragma unroll
    for (int oi = 0; oi < 2; oi++) {
      int oo = (wv & 3) * 2 + oi;
      uint4 v0 = {0, 0, 0, 0}, v1 = {0, 0, 0, 0};
      if (ih >= 0) {
        const float* sp = X + ((size_t)(b * CIN + oo * 8) * H_ + ih) * W_ + 2 * l;
        float2 tt[8];
        #pragma unroll
        for (int j = 0; j < 8; j++) tt[j] = *(const float2*)(sp + (size_t)j * HW_);
        v0.x = pk2(tt[0].x, tt[1].x); v0.y = pk2(tt[2].x, tt[3].x);
        v0.z = pk2(tt[4].x, tt[5].x); v0.w = pk2(tt[6].x, tt[7].x);
        v1.x = pk2(tt[0].y, tt[1].y); v1.y = pk2(tt[2].y, tt[3].y);
        v1.z = pk2(tt[4].y, tt[5].y); v1.w = pk2(tt[6].y, tt[7].y);
      }
      *(uint4*)(dr + wp0 * 64 + ((oo ^ (wp0 & 7)) << 3)) = v0;
      *(uint4*)(dr + wp1 * 64 + ((oo ^ (wp1 & 7)) << 3)) = v1;
    }
  }
  __syncthreads();

  const unsigned short* wb9 = Wb + (size_t)b * 9 * 4096;

  float2 st[8];
  int sb = 0;                                // (2k) % 6

  #pragma unroll 1
  for (int k = 0; k < 8; k++) {
    // (1) convert + ds_write rows staged last step (g = 2k+2+a)
    if (k > 0) {
      int sw = sb + 2 + a; if (sw >= 6) sw -= 6;
      unsigned short* dr = Xs + sw * SLOT;
      uint4 v0, v1;
      v0.x = pk2(st[0].x, st[1].x); v0.y = pk2(st[2].x, st[3].x);
      v0.z = pk2(st[4].x, st[5].x); v0.w = pk2(st[6].x, st[7].x);
      v1.x = pk2(st[0].y, st[1].y); v1.y = pk2(st[2].y, st[3].y);
      v1.z = pk2(st[4].y, st[5].y); v1.w = pk2(st[6].y, st[7].y);
      *(uint4*)(dr + wp0 * 64 + sw0) = v0;
      *(uint4*)(dr + wp1 * 64 + sw1) = v1;
    }
    // (2) raw barrier: drain only LDS writes; global stores/loads stay in flight
    asm volatile("s_waitcnt lgkmcnt(0)" ::: "memory");
    __builtin_amdgcn_s_barrier();
    __builtin_amdgcn_sched_barrier(0);

    // (3) issue next rows' loads (g = 2k+4+a); consumed next step top
    if (k < 7) {
      int ih = h0 + 2 * k + 3 + a;
      if (ih <= 127) {
        const float* sp = X + ((size_t)(b * CIN + o * 8) * H_ + ih) * W_ + 2 * l;
        #pragma unroll
        for (int j = 0; j < 8; j++) st[j] = *(const float2*)(sp + (size_t)j * HW_);
      } else {
        #pragma unroll
        for (int j = 0; j < 8; j++) st[j] = (float2){0.f, 0.f};
      }
    }
    __builtin_amdgcn_sched_barrier(0);

    // (4) compute 9 taps from ring slots (sb + rbase + kh) % 6
    f32x4 acc[4];
    #pragma unroll
    for (int nt = 0; nt < 4; nt++) acc[nt] = (f32x4){0.f, 0.f, 0.f, 0.f};

    #pragma unroll 1
    for (int kh = 0; kh < 3; kh++) {
      int r6 = sb + rbase + kh; if (r6 >= 6) r6 -= 6;
      const unsigned short* rp = Xs + r6 * SLOT;
      #pragma unroll
      for (int kw = 0; kw < 3; kw++) {
        const unsigned short* wk = wb9 + (kh * 3 + kw) * 4096;
        #pragma unroll
        for (int ck = 0; ck < 2; ck++) {
          bf16x8 af = *(const bf16x8*)(wk + (ck * 4 + cq4) * 512 + l * 8);
          bf16x8 bfr[4];
          #pragma unroll
          for (int nt = 0; nt < 4; nt++) {
            int c = cbase0 + nt * 16 + kw;
            int blk = (ck * 4 + q) ^ (c & 7);
            bfr[nt] = *(const bf16x8*)(rp + c * 64 + blk * 8);
          }
          __builtin_amdgcn_s_setprio(1);
          #pragma unroll
          for (int nt = 0; nt < 4; nt++)
            acc[nt] = __builtin_amdgcn_mfma_f32_16x16x32_bf16(
                af, bfr[nt], acc[nt], 0, 0, 0);
          __builtin_amdgcn_s_setprio(0);
        }
      }
    }

    // (5) store this step's 2 output rows (drain lazily under next compute)
    int oh = h0 + 2 * k + rbase;
    #pragma unroll
    for (int nt = 0; nt < 4; nt++) {
      int ow = cbase0 + nt * 16;
      #pragma unroll
      for (int r = 0; r < 4; r++) {
        int cout = cq4 * 16 + q * 4 + r;
        out[(((size_t)b * COUT + cout) * H_ + oh) * W_ + ow] = acc[nt][r];
      }
    }

    sb += 2; if (sb >= 6) sb -= 6;
  }
}

extern "C" void kernel_launch(void* const* d_in, const int* in_sizes, int n_in,
                              void* d_out, int out_size, void* d_ws, size_t ws_size,
                              hipStream_t stream) {
  const float* x   = (const float*)d_in[0];
  const float* cov = (const float*)d_in[1];
  const float* W0  = (const float*)d_in[2];
  const float* W1  = (const float*)d_in[3];
  float* out = (float*)d_out;

  unsigned short* Wb = (unsigned short*)d_ws;   // 32*9*64*64*2 = 4,718,592 B

  prep_w    <<<dim3(4608), dim3(256),  0, stream>>>(W0, W1, cov, Wb);
  conv_strip<<<dim3(256),  dim3(1024), 0, stream>>>(x, Wb, out);
}